// Round 5
// baseline (413.131 us; speedup 1.0000x reference)
//
#include <hip/hip_runtime.h>

#define BB 32
#define TT 1024
#define ENCD 1024
#define DECD 1024
#define MELD 80
#define KTOT (MELD + ENCD + DECD)   // 2128
#define NZ (4 * DECD)               // 4096
#define KCH 136                     // k-rows per zmm chunk (16 chunks; last = 88)
#define KC 16                       // number of zmm k-chunks
#define NTT 32                      // context t-chunks (32 rows each)
#define QR 4                        // rows per attn phase (double-buffered)

// ---- static device scratch ----
__device__ float g_cp[NTT * BB * ENCD];  // context partials [tt][b][d] (4 MB)
__device__ float g_m[NTT * BB];          // per-chunk max
__device__ float g_s[NTT * BB];          // per-chunk exp-sum (at that max)
__device__ float g_ctx[BB * ENCD];
__device__ float g_zp[KC * BB * NZ];     // z partials [kc][b][j] (8.4 MB)
__device__ float g_hn[BB * DECD];
__device__ int   g_cnt[BB];              // last-block-done counters (self-resetting)

__device__ __forceinline__ float tanh_fast(float x) {
    // 1 - 2/(e+1): exact +-1 limits (rcp(inf)=0)
    return 1.f - __fdividef(2.f, __expf(2.f * x) + 1.f);
}
__device__ __forceinline__ float sigmoid_fast(float x) {
    return __fdividef(1.f, 1.f + __expf(-x));
}

// ---------------------------------------------------------------------------
// K1: one-pass attention, double-buffered QR=4 phases + fused final combine.
// grid (b=32, tc=32) = 1024 blocks (4/CU via 33KB LDS), 256 thr = 4 waves.
// Phase p (8 total): wave w stages row p*4+w (load->score->LDS buf[p&1]);
// single barrier per phase; next-phase loads issue BEFORE current consume so
// consume VALU hides HBM latency. Exact 4-score softmax per phase with
// running (M,S) correction. Last-done block per b (device-scope atomic +
// fences) performs the global combine -> g_ctx, replacing k_combine.
// ---------------------------------------------------------------------------
__global__ __launch_bounds__(256, 4) void k_attn(const float* __restrict__ enc,
                                                 const float* __restrict__ hst,
                                                 const float* __restrict__ scale) {
    __shared__ float es[2][QR][ENCD];   // 32 KB
    __shared__ float ssc[2][QR];
    __shared__ int lastFlag;
    __shared__ float wgt[NTT];
    int b = blockIdx.x, tc = blockIdx.y;
    int tid = threadIdx.x, w = tid >> 6, lane = tid & 63;
    const float4* hp = (const float4*)(hst + (size_t)b * DECD);
    const float4* sp = (const float4*)scale;
    float4 hr0 = hp[lane], hr1 = hp[lane + 64], hr2 = hp[lane + 128], hr3 = hp[lane + 192];
    float4 sr0 = sp[lane], sr1 = sp[lane + 64], sr2 = sp[lane + 128], sr3 = sp[lane + 192];

    float M = -1e30f, S = 0.f;
    float cx = 0.f, cy = 0.f, cz = 0.f, cw = 0.f;
    const float4* ebase = (const float4*)(enc + ((size_t)b * TT + tc * 32) * ENCD);

    // stage row (p*QR + w) of this 32-row chunk into buffer `buf`
    auto stage = [&](int p, int buf) {
        const float4* ep = ebase + (size_t)(p * QR + w) * (ENCD / 4) + lane;
        float4 e0 = ep[0], e1 = ep[64], e2 = ep[128], e3 = ep[192];
        float sc = 0.f;
        sc = fmaf(sr0.x, tanh_fast(hr0.x + e0.x), sc);
        sc = fmaf(sr0.y, tanh_fast(hr0.y + e0.y), sc);
        sc = fmaf(sr0.z, tanh_fast(hr0.z + e0.z), sc);
        sc = fmaf(sr0.w, tanh_fast(hr0.w + e0.w), sc);
        sc = fmaf(sr1.x, tanh_fast(hr1.x + e1.x), sc);
        sc = fmaf(sr1.y, tanh_fast(hr1.y + e1.y), sc);
        sc = fmaf(sr1.z, tanh_fast(hr1.z + e1.z), sc);
        sc = fmaf(sr1.w, tanh_fast(hr1.w + e1.w), sc);
        sc = fmaf(sr2.x, tanh_fast(hr2.x + e2.x), sc);
        sc = fmaf(sr2.y, tanh_fast(hr2.y + e2.y), sc);
        sc = fmaf(sr2.z, tanh_fast(hr2.z + e2.z), sc);
        sc = fmaf(sr2.w, tanh_fast(hr2.w + e2.w), sc);
        sc = fmaf(sr3.x, tanh_fast(hr3.x + e3.x), sc);
        sc = fmaf(sr3.y, tanh_fast(hr3.y + e3.y), sc);
        sc = fmaf(sr3.z, tanh_fast(hr3.z + e3.z), sc);
        sc = fmaf(sr3.w, tanh_fast(hr3.w + e3.w), sc);
#pragma unroll
        for (int off = 32; off; off >>= 1) sc += __shfl_xor(sc, off, 64);
        float4* esr = (float4*)&es[buf][w][0];
        esr[lane] = e0; esr[lane + 64] = e1;
        esr[lane + 128] = e2; esr[lane + 192] = e3;
        if (lane == 0) ssc[buf][w] = sc;
    };
    // consume buffer `buf`: softmax over its 4 scores + ctx accumulate
    auto consume = [&](int buf) {
        float s0 = ssc[buf][0], s1 = ssc[buf][1], s2 = ssc[buf][2], s3 = ssc[buf][3];
        float mq = fmaxf(fmaxf(s0, s1), fmaxf(s2, s3));
        float Mn = fmaxf(M, mq);
        float alO = __expf(M - Mn);          // first phase: exp(-inf) = 0
        float w0 = __expf(s0 - Mn), w1 = __expf(s1 - Mn);
        float w2 = __expf(s2 - Mn), w3 = __expf(s3 - Mn);
        S = fmaf(S, alO, (w0 + w1) + (w2 + w3));
        M = Mn;
        cx *= alO; cy *= alO; cz *= alO; cw *= alO;
        const float4* col = (const float4*)&es[buf][0][0] + tid;  // row stride 256 f4
        float4 e;
        e = col[0];   cx = fmaf(w0, e.x, cx); cy = fmaf(w0, e.y, cy);
                      cz = fmaf(w0, e.z, cz); cw = fmaf(w0, e.w, cw);
        e = col[256]; cx = fmaf(w1, e.x, cx); cy = fmaf(w1, e.y, cy);
                      cz = fmaf(w1, e.z, cz); cw = fmaf(w1, e.w, cw);
        e = col[512]; cx = fmaf(w2, e.x, cx); cy = fmaf(w2, e.y, cy);
                      cz = fmaf(w2, e.z, cz); cw = fmaf(w2, e.w, cw);
        e = col[768]; cx = fmaf(w3, e.x, cx); cy = fmaf(w3, e.y, cy);
                      cz = fmaf(w3, e.z, cz); cw = fmaf(w3, e.w, cw);
    };

    stage(0, 0);
    __syncthreads();
#pragma unroll
    for (int p = 0; p < 8; p++) {
        if (p < 7) stage(p + 1, (p + 1) & 1);   // loads issue before consume VALU
        consume(p & 1);
        __syncthreads();
    }

    float4 r4; r4.x = cx; r4.y = cy; r4.z = cz; r4.w = cw;
    ((float4*)g_cp)[((size_t)tc * BB + b) * (ENCD / 4) + tid] = r4;
    if (tid == 0) { g_m[tc * BB + b] = M; g_s[tc * BB + b] = S; }

    // ---- last-done block for this b performs the global combine ----
    __threadfence();                 // release our partial writes (device scope)
    __syncthreads();                 // all threads' writes+fences done
    if (tid == 0) lastFlag = (atomicAdd(&g_cnt[b], 1) == NTT - 1);
    __syncthreads();
    if (!lastFlag) return;
    if (tid == 0) g_cnt[b] = 0;      // self-reset for next graph replay
    __threadfence();                 // acquire: see all blocks' partials
    float Mg = -1e30f;
#pragma unroll
    for (int tt = 0; tt < NTT; tt++) Mg = fmaxf(Mg, g_m[tt * BB + b]);
    float Sg = 0.f;
#pragma unroll
    for (int tt = 0; tt < NTT; tt++) Sg += g_s[tt * BB + b] * __expf(g_m[tt * BB + b] - Mg);
    if (tid < NTT) wgt[tid] = __expf(g_m[tid * BB + b] - Mg) * __fdividef(1.f, Sg);
    __syncthreads();
    const float4* cp = (const float4*)g_cp + (size_t)b * (ENCD / 4) + tid;
    float ax = 0.f, ay = 0.f, az = 0.f, aw = 0.f;
#pragma unroll 8
    for (int tt = 0; tt < NTT; tt++) {
        float4 v = cp[(size_t)tt * (BB * ENCD / 4)];
        float wv = wgt[tt];
        ax = fmaf(wv, v.x, ax); ay = fmaf(wv, v.y, ay);
        az = fmaf(wv, v.z, az); aw = fmaf(wv, v.w, aw);
    }
    float4 r; r.x = ax; r.y = ay; r.z = az; r.w = aw;
    ((float4*)g_ctx)[b * (ENCD / 4) + tid] = r;
}

// ---------------------------------------------------------------------------
// K3: z partials. grid 512 = 32 jt (128 j) x 16 kc (KCH=136; last = 88).
// Exactly 2 blocks/CU (no tail), 8 waves/CU for latency hiding.
// 256 thr = 128 j x 2 k-halves (rows 72/64; last chunk 48/40, all /8).
// x staged in LDS for all 32 batches; halves LDS-combined before store.
// ---------------------------------------------------------------------------
__global__ __launch_bounds__(256) void k_zmm(const float* __restrict__ pm,
                                             const float* __restrict__ h,
                                             const float* __restrict__ kern,
                                             const float* __restrict__ reck) {
    __shared__ float xs[KCH * 32];       // 17.4 KB
    __shared__ float sacc[32 * 128];     // 16 KB: khalf-1 partials [b][jl]
    int jt = blockIdx.x & 31, kc = blockIdx.x >> 5;
    int k0 = kc * KCH;
    int kcount = min(KCH, KTOT - k0);    // 136 or 88
    int tid = threadIdx.x;
    for (int idx = tid; idx < kcount * 32; idx += 256) {
        int kk = idx >> 5, b = idx & 31;
        int k = k0 + kk;
        float v;
        if (k < MELD)             v = pm[b * MELD + k];
        else if (k < MELD + ENCD) v = g_ctx[b * ENCD + (k - MELD)];
        else                      v = h[b * DECD + (k - MELD - ENCD)];
        xs[idx] = v;
    }
    __syncthreads();
    int jl = tid & 127, kh = tid >> 7;
    int j = jt * 128 + jl;
    int split = (kcount == KCH) ? 72 : 48;    // both halves divisible by 8
    int kb = kh ? split : 0;
    int ke = kh ? kcount : split;
    float acc[32];
#pragma unroll
    for (int b = 0; b < 32; b++) acc[b] = 0.f;
    for (int kk0 = kb; kk0 < ke; kk0 += 8) {
        float w[8];
#pragma unroll
        for (int i = 0; i < 8; i++) {
            int k = k0 + kk0 + i;
            w[i] = (k < MELD + ENCD) ? kern[(size_t)k * NZ + j]
                                     : reck[(size_t)(k - MELD - ENCD) * NZ + j];
        }
#pragma unroll
        for (int i = 0; i < 8; i++) {
            const float* xr = xs + (kk0 + i) * 32;
#pragma unroll
            for (int b = 0; b < 32; b++) acc[b] = fmaf(xr[b], w[i], acc[b]);
        }
    }
    if (kh) {
#pragma unroll
        for (int b = 0; b < 32; b++) sacc[b * 128 + jl] = acc[b];
    }
    __syncthreads();
    if (!kh) {
#pragma unroll
        for (int b = 0; b < 32; b++)
            g_zp[((size_t)kc * BB + b) * NZ + j] = acc[b] + sacc[b * 128 + jl];
    }
}

// ---------------------------------------------------------------------------
// K4: sum z partials + bias, gates -> h_new/c_new (fp32 out).
// grid 512 = 32 b x 16 jt (j-tile 64); kc-sum (16 chunks) split 4/4/4/4
// across thread groups, LDS reduce. out: mel[0,2560) h[2560,35328) c[35328,..)
// ---------------------------------------------------------------------------
__global__ __launch_bounds__(256) void k_gates(const float* __restrict__ bias,
                                               const float* __restrict__ c,
                                               float* __restrict__ out) {
    __shared__ float sacc[4][4][64];   // [grp][gate][jl]
    int b = blockIdx.x >> 4, jq = blockIdx.x & 15;
    int jl = threadIdx.x & 63, grp = threadIdx.x >> 6;
    int j = jq * 64 + jl;
    int kc0 = grp * 4;
    int kc1 = kc0 + 4;
    float zi = 0.f, zf = 0.f, zg = 0.f, zo = 0.f;
    for (int kc = kc0; kc < kc1; kc++) {
        const float* zp = g_zp + ((size_t)kc * BB + b) * NZ;
        zi += zp[j];
        zf += zp[1024 + j];
        zg += zp[2048 + j];
        zo += zp[3072 + j];
    }
    sacc[grp][0][jl] = zi; sacc[grp][1][jl] = zf;
    sacc[grp][2][jl] = zg; sacc[grp][3][jl] = zo;
    __syncthreads();
    if (grp == 0) {
        zi = sacc[0][0][jl] + sacc[1][0][jl] + sacc[2][0][jl] + sacc[3][0][jl] + bias[j];
        zf = sacc[0][1][jl] + sacc[1][1][jl] + sacc[2][1][jl] + sacc[3][1][jl] + bias[1024 + j];
        zg = sacc[0][2][jl] + sacc[1][2][jl] + sacc[2][2][jl] + sacc[3][2][jl] + bias[2048 + j];
        zo = sacc[0][3][jl] + sacc[1][3][jl] + sacc[2][3][jl] + sacc[3][3][jl] + bias[3072 + j];
        int idx = b * 1024 + j;
        float cn = sigmoid_fast(zf) * c[idx] + sigmoid_fast(zi) * tanh_fast(zg);
        float hn = sigmoid_fast(zo) * tanh_fast(cn);
        g_hn[idx] = hn;
        out[2560 + idx] = hn;
        out[35328 + idx] = cn;
    }
}

// ---------------------------------------------------------------------------
// K5: mel[b,m] = h_new[b,:] @ proj_w[:,m] + proj_b[m]
// grid 32; 160 active threads = 80 m x 2 d-halves, LDS combine.
// ---------------------------------------------------------------------------
__global__ __launch_bounds__(256) void k_proj(const float* __restrict__ pw,
                                              const float* __restrict__ pb,
                                              float* __restrict__ out) {
    __shared__ float lh[1024];
    __shared__ float pacc[2][MELD];
    int b = blockIdx.x, tid = threadIdx.x;
    for (int i = tid; i < 1024; i += 256) lh[i] = g_hn[b * 1024 + i];
    __syncthreads();
    int m = tid & 127;
    int g = tid >> 7;
    if (m < MELD) {
        float acc = 0.f;
        int d0 = g * 512;
#pragma unroll 8
        for (int d = d0; d < d0 + 512; d++) acc = fmaf(lh[d], pw[d * MELD + m], acc);
        pacc[g][m] = acc;
    }
    __syncthreads();
    if (tid < MELD) out[b * MELD + tid] = pacc[0][tid] + pacc[1][tid] + pb[tid];
}

extern "C" void kernel_launch(void* const* d_in, const int* in_sizes, int n_in,
                              void* d_out, int out_size, void* d_ws, size_t ws_size,
                              hipStream_t stream) {
    const float* pm   = (const float*)d_in[0];   // prev_mel_frame [32,80]
    const float* enc  = (const float*)d_in[1];   // encoder_outputs [32,1024,1024]
    const float* h    = (const float*)d_in[2];   // h [32,1024]
    const float* c    = (const float*)d_in[3];   // c [32,1024]
    const float* asc  = (const float*)d_in[4];   // attn_scale [1024]
    const float* kern = (const float*)d_in[5];   // kernel [1104,4096]
    const float* reck = (const float*)d_in[6];   // rec_kernel [1024,4096]
    const float* bias = (const float*)d_in[7];   // bias [4096]
    const float* pw   = (const float*)d_in[8];   // proj_w [1024,80]
    const float* pb   = (const float*)d_in[9];   // proj_b [80]
    float* out = (float*)d_out;                  // fp32: mel | h_new | c_new

    k_attn   <<<dim3(32, NTT), 256, 0, stream>>>(enc, h, asc);
    k_zmm    <<<512, 256, 0, stream>>>(pm, h, kern, reck);
    k_gates  <<<512, 256, 0, stream>>>(bias, c, out);
    k_proj   <<<32, 256, 0, stream>>>(pw, pb, out);
}

// Round 6
// 287.859 us; speedup vs baseline: 1.4352x; 1.4352x over previous
//
#include <hip/hip_runtime.h>

#define BB 32
#define TT 1024
#define ENCD 1024
#define DECD 1024
#define MELD 80
#define KTOT (MELD + ENCD + DECD)   // 2128
#define NZ (4 * DECD)               // 4096
#define KCH 136                     // k-rows per zmm chunk (16 chunks; last = 88)
#define KC 16                       // number of zmm k-chunks
#define NTT 32                      // context t-chunks (32 rows each)
#define QR 4                        // rows per attn phase (double-buffered)

// ---- static device scratch ----
__device__ float g_cp[NTT * BB * ENCD];  // context partials [tt][b][d] (4 MB)
__device__ float g_m[NTT * BB];          // per-chunk max
__device__ float g_s[NTT * BB];          // per-chunk exp-sum (at that max)
__device__ float g_ctx[BB * ENCD];
__device__ float g_zp[KC * BB * NZ];     // z partials [kc][b][j] (8.4 MB)
__device__ float g_hn[BB * DECD];

__device__ __forceinline__ float tanh_fast(float x) {
    // 1 - 2/(e+1): exact +-1 limits (rcp(inf)=0)
    return 1.f - __fdividef(2.f, __expf(2.f * x) + 1.f);
}
__device__ __forceinline__ float sigmoid_fast(float x) {
    return __fdividef(1.f, 1.f + __expf(-x));
}

// ---------------------------------------------------------------------------
// K1: one-pass attention, double-buffered QR=4 phases. NO device-scope
// fences/atomics (round-5 lesson: agent-scope __threadfence => buffer_wbl2
// L2-writeback per block = 200us of cache maintenance; the fused combine
// is NOT worth it). Partials go to g_cp/g_m/g_s; separate k_combine reduces.
// grid (b=32, tc=32) = 1024 blocks (4/CU via 32KB LDS), 256 thr = 4 waves.
// Phase p (8 total): wave w stages row p*4+w (load->score->LDS buf[p&1]);
// single barrier per phase; next-phase loads issue before current consume.
// ---------------------------------------------------------------------------
__global__ __launch_bounds__(256, 4) void k_attn(const float* __restrict__ enc,
                                                 const float* __restrict__ hst,
                                                 const float* __restrict__ scale) {
    __shared__ float es[2][QR][ENCD];   // 32 KB
    __shared__ float ssc[2][QR];
    int b = blockIdx.x, tc = blockIdx.y;
    int tid = threadIdx.x, w = tid >> 6, lane = tid & 63;
    const float4* hp = (const float4*)(hst + (size_t)b * DECD);
    const float4* sp = (const float4*)scale;
    float4 hr0 = hp[lane], hr1 = hp[lane + 64], hr2 = hp[lane + 128], hr3 = hp[lane + 192];
    float4 sr0 = sp[lane], sr1 = sp[lane + 64], sr2 = sp[lane + 128], sr3 = sp[lane + 192];

    float M = -1e30f, S = 0.f;
    float cx = 0.f, cy = 0.f, cz = 0.f, cw = 0.f;
    const float4* ebase = (const float4*)(enc + ((size_t)b * TT + tc * 32) * ENCD);

    // stage row (p*QR + w) of this 32-row chunk into buffer `buf`
    auto stage = [&](int p, int buf) {
        const float4* ep = ebase + (size_t)(p * QR + w) * (ENCD / 4) + lane;
        float4 e0 = ep[0], e1 = ep[64], e2 = ep[128], e3 = ep[192];
        float sc = 0.f;
        sc = fmaf(sr0.x, tanh_fast(hr0.x + e0.x), sc);
        sc = fmaf(sr0.y, tanh_fast(hr0.y + e0.y), sc);
        sc = fmaf(sr0.z, tanh_fast(hr0.z + e0.z), sc);
        sc = fmaf(sr0.w, tanh_fast(hr0.w + e0.w), sc);
        sc = fmaf(sr1.x, tanh_fast(hr1.x + e1.x), sc);
        sc = fmaf(sr1.y, tanh_fast(hr1.y + e1.y), sc);
        sc = fmaf(sr1.z, tanh_fast(hr1.z + e1.z), sc);
        sc = fmaf(sr1.w, tanh_fast(hr1.w + e1.w), sc);
        sc = fmaf(sr2.x, tanh_fast(hr2.x + e2.x), sc);
        sc = fmaf(sr2.y, tanh_fast(hr2.y + e2.y), sc);
        sc = fmaf(sr2.z, tanh_fast(hr2.z + e2.z), sc);
        sc = fmaf(sr2.w, tanh_fast(hr2.w + e2.w), sc);
        sc = fmaf(sr3.x, tanh_fast(hr3.x + e3.x), sc);
        sc = fmaf(sr3.y, tanh_fast(hr3.y + e3.y), sc);
        sc = fmaf(sr3.z, tanh_fast(hr3.z + e3.z), sc);
        sc = fmaf(sr3.w, tanh_fast(hr3.w + e3.w), sc);
#pragma unroll
        for (int off = 32; off; off >>= 1) sc += __shfl_xor(sc, off, 64);
        float4* esr = (float4*)&es[buf][w][0];
        esr[lane] = e0; esr[lane + 64] = e1;
        esr[lane + 128] = e2; esr[lane + 192] = e3;
        if (lane == 0) ssc[buf][w] = sc;
    };
    // consume buffer `buf`: softmax over its 4 scores + ctx accumulate
    auto consume = [&](int buf) {
        float s0 = ssc[buf][0], s1 = ssc[buf][1], s2 = ssc[buf][2], s3 = ssc[buf][3];
        float mq = fmaxf(fmaxf(s0, s1), fmaxf(s2, s3));
        float Mn = fmaxf(M, mq);
        float alO = __expf(M - Mn);          // first phase: exp(-inf) = 0
        float w0 = __expf(s0 - Mn), w1 = __expf(s1 - Mn);
        float w2 = __expf(s2 - Mn), w3 = __expf(s3 - Mn);
        S = fmaf(S, alO, (w0 + w1) + (w2 + w3));
        M = Mn;
        cx *= alO; cy *= alO; cz *= alO; cw *= alO;
        const float4* col = (const float4*)&es[buf][0][0] + tid;  // row stride 256 f4
        float4 e;
        e = col[0];   cx = fmaf(w0, e.x, cx); cy = fmaf(w0, e.y, cy);
                      cz = fmaf(w0, e.z, cz); cw = fmaf(w0, e.w, cw);
        e = col[256]; cx = fmaf(w1, e.x, cx); cy = fmaf(w1, e.y, cy);
                      cz = fmaf(w1, e.z, cz); cw = fmaf(w1, e.w, cw);
        e = col[512]; cx = fmaf(w2, e.x, cx); cy = fmaf(w2, e.y, cy);
                      cz = fmaf(w2, e.z, cz); cw = fmaf(w2, e.w, cw);
        e = col[768]; cx = fmaf(w3, e.x, cx); cy = fmaf(w3, e.y, cy);
                      cz = fmaf(w3, e.z, cz); cw = fmaf(w3, e.w, cw);
    };

    stage(0, 0);
    __syncthreads();
#pragma unroll
    for (int p = 0; p < 8; p++) {
        if (p < 7) stage(p + 1, (p + 1) & 1);   // loads issue before consume VALU
        consume(p & 1);
        __syncthreads();
    }

    float4 r4; r4.x = cx; r4.y = cy; r4.z = cz; r4.w = cw;
    ((float4*)g_cp)[((size_t)tc * BB + b) * (ENCD / 4) + tid] = r4;
    if (tid == 0) { g_m[tc * BB + b] = M; g_s[tc * BB + b] = S; }
}

// ---------------------------------------------------------------------------
// K2: combine 32 chunk partials per batch with global max/sum correction.
// grid (32 b, 8 dq) = 256 blocks x 128 thr = 1 block/CU; thread owns one d.
// ---------------------------------------------------------------------------
__global__ __launch_bounds__(128) void k_combine() {
    __shared__ float wgt[NTT];
    int b = blockIdx.x, dq = blockIdx.y, tid = threadIdx.x;
    float M = -1e30f;
#pragma unroll
    for (int tt = 0; tt < NTT; tt++) M = fmaxf(M, g_m[tt * BB + b]);
    float S = 0.f;
#pragma unroll
    for (int tt = 0; tt < NTT; tt++) S += g_s[tt * BB + b] * __expf(g_m[tt * BB + b] - M);
    if (tid < NTT) wgt[tid] = __expf(g_m[tid * BB + b] - M) * __fdividef(1.f, S);
    __syncthreads();
    int d = dq * 128 + tid;
    float acc = 0.f;
#pragma unroll 8
    for (int tt = 0; tt < NTT; tt++)
        acc = fmaf(wgt[tt], g_cp[((size_t)tt * BB + b) * ENCD + d], acc);
    g_ctx[b * ENCD + d] = acc;
}

// ---------------------------------------------------------------------------
// K3: z partials. grid 512 = 32 jt (128 j) x 16 kc (KCH=136; last = 88).
// Exactly 2 blocks/CU (no tail), 8 waves/CU for latency hiding.
// 256 thr = 128 j x 2 k-halves (rows 72/64; last chunk 48/40, all /8).
// x staged in LDS for all 32 batches; halves LDS-combined before store.
// ---------------------------------------------------------------------------
__global__ __launch_bounds__(256) void k_zmm(const float* __restrict__ pm,
                                             const float* __restrict__ h,
                                             const float* __restrict__ kern,
                                             const float* __restrict__ reck) {
    __shared__ float xs[KCH * 32];       // 17.4 KB
    __shared__ float sacc[32 * 128];     // 16 KB: khalf-1 partials [b][jl]
    int jt = blockIdx.x & 31, kc = blockIdx.x >> 5;
    int k0 = kc * KCH;
    int kcount = min(KCH, KTOT - k0);    // 136 or 88
    int tid = threadIdx.x;
    for (int idx = tid; idx < kcount * 32; idx += 256) {
        int kk = idx >> 5, b = idx & 31;
        int k = k0 + kk;
        float v;
        if (k < MELD)             v = pm[b * MELD + k];
        else if (k < MELD + ENCD) v = g_ctx[b * ENCD + (k - MELD)];
        else                      v = h[b * DECD + (k - MELD - ENCD)];
        xs[idx] = v;
    }
    __syncthreads();
    int jl = tid & 127, kh = tid >> 7;
    int j = jt * 128 + jl;
    int split = (kcount == KCH) ? 72 : 48;    // both halves divisible by 8
    int kb = kh ? split : 0;
    int ke = kh ? kcount : split;
    float acc[32];
#pragma unroll
    for (int b = 0; b < 32; b++) acc[b] = 0.f;
    for (int kk0 = kb; kk0 < ke; kk0 += 8) {
        float w[8];
#pragma unroll
        for (int i = 0; i < 8; i++) {
            int k = k0 + kk0 + i;
            w[i] = (k < MELD + ENCD) ? kern[(size_t)k * NZ + j]
                                     : reck[(size_t)(k - MELD - ENCD) * NZ + j];
        }
#pragma unroll
        for (int i = 0; i < 8; i++) {
            const float* xr = xs + (kk0 + i) * 32;
#pragma unroll
            for (int b = 0; b < 32; b++) acc[b] = fmaf(xr[b], w[i], acc[b]);
        }
    }
    if (kh) {
#pragma unroll
        for (int b = 0; b < 32; b++) sacc[b * 128 + jl] = acc[b];
    }
    __syncthreads();
    if (!kh) {
#pragma unroll
        for (int b = 0; b < 32; b++)
            g_zp[((size_t)kc * BB + b) * NZ + j] = acc[b] + sacc[b * 128 + jl];
    }
}

// ---------------------------------------------------------------------------
// K4: sum z partials + bias, gates -> h_new/c_new (fp32 out).
// grid 512 = 32 b x 16 jt (j-tile 64); kc-sum (16 chunks) split 4/4/4/4
// across thread groups, LDS reduce. out: mel[0,2560) h[2560,35328) c[35328,..)
// ---------------------------------------------------------------------------
__global__ __launch_bounds__(256) void k_gates(const float* __restrict__ bias,
                                               const float* __restrict__ c,
                                               float* __restrict__ out) {
    __shared__ float sacc[4][4][64];   // [grp][gate][jl]
    int b = blockIdx.x >> 4, jq = blockIdx.x & 15;
    int jl = threadIdx.x & 63, grp = threadIdx.x >> 6;
    int j = jq * 64 + jl;
    int kc0 = grp * 4;
    int kc1 = kc0 + 4;
    float zi = 0.f, zf = 0.f, zg = 0.f, zo = 0.f;
    for (int kc = kc0; kc < kc1; kc++) {
        const float* zp = g_zp + ((size_t)kc * BB + b) * NZ;
        zi += zp[j];
        zf += zp[1024 + j];
        zg += zp[2048 + j];
        zo += zp[3072 + j];
    }
    sacc[grp][0][jl] = zi; sacc[grp][1][jl] = zf;
    sacc[grp][2][jl] = zg; sacc[grp][3][jl] = zo;
    __syncthreads();
    if (grp == 0) {
        zi = sacc[0][0][jl] + sacc[1][0][jl] + sacc[2][0][jl] + sacc[3][0][jl] + bias[j];
        zf = sacc[0][1][jl] + sacc[1][1][jl] + sacc[2][1][jl] + sacc[3][1][jl] + bias[1024 + j];
        zg = sacc[0][2][jl] + sacc[1][2][jl] + sacc[2][2][jl] + sacc[3][2][jl] + bias[2048 + j];
        zo = sacc[0][3][jl] + sacc[1][3][jl] + sacc[2][3][jl] + sacc[3][3][jl] + bias[3072 + j];
        int idx = b * 1024 + j;
        float cn = sigmoid_fast(zf) * c[idx] + sigmoid_fast(zi) * tanh_fast(zg);
        float hn = sigmoid_fast(zo) * tanh_fast(cn);
        g_hn[idx] = hn;
        out[2560 + idx] = hn;
        out[35328 + idx] = cn;
    }
}

// ---------------------------------------------------------------------------
// K5: mel[b,m] = h_new[b,:] @ proj_w[:,m] + proj_b[m]
// grid 32; 160 active threads = 80 m x 2 d-halves, LDS combine.
// ---------------------------------------------------------------------------
__global__ __launch_bounds__(256) void k_proj(const float* __restrict__ pw,
                                              const float* __restrict__ pb,
                                              float* __restrict__ out) {
    __shared__ float lh[1024];
    __shared__ float pacc[2][MELD];
    int b = blockIdx.x, tid = threadIdx.x;
    for (int i = tid; i < 1024; i += 256) lh[i] = g_hn[b * 1024 + i];
    __syncthreads();
    int m = tid & 127;
    int g = tid >> 7;
    if (m < MELD) {
        float acc = 0.f;
        int d0 = g * 512;
#pragma unroll 8
        for (int d = d0; d < d0 + 512; d++) acc = fmaf(lh[d], pw[d * MELD + m], acc);
        pacc[g][m] = acc;
    }
    __syncthreads();
    if (tid < MELD) out[b * MELD + tid] = pacc[0][tid] + pacc[1][tid] + pb[tid];
}

extern "C" void kernel_launch(void* const* d_in, const int* in_sizes, int n_in,
                              void* d_out, int out_size, void* d_ws, size_t ws_size,
                              hipStream_t stream) {
    const float* pm   = (const float*)d_in[0];   // prev_mel_frame [32,80]
    const float* enc  = (const float*)d_in[1];   // encoder_outputs [32,1024,1024]
    const float* h    = (const float*)d_in[2];   // h [32,1024]
    const float* c    = (const float*)d_in[3];   // c [32,1024]
    const float* asc  = (const float*)d_in[4];   // attn_scale [1024]
    const float* kern = (const float*)d_in[5];   // kernel [1104,4096]
    const float* reck = (const float*)d_in[6];   // rec_kernel [1024,4096]
    const float* bias = (const float*)d_in[7];   // bias [4096]
    const float* pw   = (const float*)d_in[8];   // proj_w [1024,80]
    const float* pb   = (const float*)d_in[9];   // proj_b [80]
    float* out = (float*)d_out;                  // fp32: mel | h_new | c_new

    k_attn   <<<dim3(32, NTT), 256, 0, stream>>>(enc, h, asc);
    k_combine<<<dim3(32, 8), 128, 0, stream>>>();
    k_zmm    <<<512, 256, 0, stream>>>(pm, h, kern, reck);
    k_gates  <<<512, 256, 0, stream>>>(bias, c, out);
    k_proj   <<<32, 256, 0, stream>>>(pw, pb, out);
}

// Round 7
// 257.680 us; speedup vs baseline: 1.6033x; 1.1171x over previous
//
#include <hip/hip_runtime.h>

#define BB 32
#define TT 1024
#define ENCD 1024
#define DECD 1024
#define MELD 80
#define KTOT (MELD + ENCD + DECD)   // 2128
#define NZ (4 * DECD)               // 4096
#define KCH 136                     // k-rows per zmm chunk (16 chunks; last = 88)
#define KC 16                       // number of zmm k-chunks
#define NTT 32                      // context t-chunks (32 rows each)
#define QR 4                        // rows per attn phase (double-buffered)

// ---- static device scratch ----
__device__ float g_cp[NTT * BB * ENCD];  // context partials [tt][b][d] (4 MB)
__device__ float g_m[NTT * BB];          // per-chunk max
__device__ float g_s[NTT * BB];          // per-chunk exp-sum (at that max)
__device__ float g_ctx[BB * ENCD];
__device__ float g_zp[KC * BB * NZ];     // z partials [kc][b][j] (8.4 MB)

__device__ __forceinline__ float tanh_fast(float x) {
    // 1 - 2/(e+1): exact +-1 limits (rcp(inf)=0)
    return 1.f - __fdividef(2.f, __expf(2.f * x) + 1.f);
}
__device__ __forceinline__ float sigmoid_fast(float x) {
    return __fdividef(1.f, 1.f + __expf(-x));
}

// ---------------------------------------------------------------------------
// K1: one-pass attention, double-buffered QR=4 phases. NO device-scope
// fences/atomics (round-5 lesson: agent-scope __threadfence => buffer_wbl2
// L2-writeback per block = 200us of cache maintenance).
// grid (b=32, tc=32) = 1024 blocks (4/CU via 32KB LDS), 256 thr = 4 waves.
// Phase p (8 total): wave w stages row p*4+w (load->score->LDS buf[p&1]);
// single barrier per phase; next-phase loads issue before current consume.
// ---------------------------------------------------------------------------
__global__ __launch_bounds__(256, 4) void k_attn(const float* __restrict__ enc,
                                                 const float* __restrict__ hst,
                                                 const float* __restrict__ scale) {
    __shared__ float es[2][QR][ENCD];   // 32 KB
    __shared__ float ssc[2][QR];
    int b = blockIdx.x, tc = blockIdx.y;
    int tid = threadIdx.x, w = tid >> 6, lane = tid & 63;
    const float4* hp = (const float4*)(hst + (size_t)b * DECD);
    const float4* sp = (const float4*)scale;
    float4 hr0 = hp[lane], hr1 = hp[lane + 64], hr2 = hp[lane + 128], hr3 = hp[lane + 192];
    float4 sr0 = sp[lane], sr1 = sp[lane + 64], sr2 = sp[lane + 128], sr3 = sp[lane + 192];

    float M = -1e30f, S = 0.f;
    float cx = 0.f, cy = 0.f, cz = 0.f, cw = 0.f;
    const float4* ebase = (const float4*)(enc + ((size_t)b * TT + tc * 32) * ENCD);

    // stage row (p*QR + w) of this 32-row chunk into buffer `buf`
    auto stage = [&](int p, int buf) {
        const float4* ep = ebase + (size_t)(p * QR + w) * (ENCD / 4) + lane;
        float4 e0 = ep[0], e1 = ep[64], e2 = ep[128], e3 = ep[192];
        float sc = 0.f;
        sc = fmaf(sr0.x, tanh_fast(hr0.x + e0.x), sc);
        sc = fmaf(sr0.y, tanh_fast(hr0.y + e0.y), sc);
        sc = fmaf(sr0.z, tanh_fast(hr0.z + e0.z), sc);
        sc = fmaf(sr0.w, tanh_fast(hr0.w + e0.w), sc);
        sc = fmaf(sr1.x, tanh_fast(hr1.x + e1.x), sc);
        sc = fmaf(sr1.y, tanh_fast(hr1.y + e1.y), sc);
        sc = fmaf(sr1.z, tanh_fast(hr1.z + e1.z), sc);
        sc = fmaf(sr1.w, tanh_fast(hr1.w + e1.w), sc);
        sc = fmaf(sr2.x, tanh_fast(hr2.x + e2.x), sc);
        sc = fmaf(sr2.y, tanh_fast(hr2.y + e2.y), sc);
        sc = fmaf(sr2.z, tanh_fast(hr2.z + e2.z), sc);
        sc = fmaf(sr2.w, tanh_fast(hr2.w + e2.w), sc);
        sc = fmaf(sr3.x, tanh_fast(hr3.x + e3.x), sc);
        sc = fmaf(sr3.y, tanh_fast(hr3.y + e3.y), sc);
        sc = fmaf(sr3.z, tanh_fast(hr3.z + e3.z), sc);
        sc = fmaf(sr3.w, tanh_fast(hr3.w + e3.w), sc);
#pragma unroll
        for (int off = 32; off; off >>= 1) sc += __shfl_xor(sc, off, 64);
        float4* esr = (float4*)&es[buf][w][0];
        esr[lane] = e0; esr[lane + 64] = e1;
        esr[lane + 128] = e2; esr[lane + 192] = e3;
        if (lane == 0) ssc[buf][w] = sc;
    };
    // consume buffer `buf`: softmax over its 4 scores + ctx accumulate
    auto consume = [&](int buf) {
        float s0 = ssc[buf][0], s1 = ssc[buf][1], s2 = ssc[buf][2], s3 = ssc[buf][3];
        float mq = fmaxf(fmaxf(s0, s1), fmaxf(s2, s3));
        float Mn = fmaxf(M, mq);
        float alO = __expf(M - Mn);          // first phase: exp(-inf) = 0
        float w0 = __expf(s0 - Mn), w1 = __expf(s1 - Mn);
        float w2 = __expf(s2 - Mn), w3 = __expf(s3 - Mn);
        S = fmaf(S, alO, (w0 + w1) + (w2 + w3));
        M = Mn;
        cx *= alO; cy *= alO; cz *= alO; cw *= alO;
        const float4* col = (const float4*)&es[buf][0][0] + tid;  // row stride 256 f4
        float4 e;
        e = col[0];   cx = fmaf(w0, e.x, cx); cy = fmaf(w0, e.y, cy);
                      cz = fmaf(w0, e.z, cz); cw = fmaf(w0, e.w, cw);
        e = col[256]; cx = fmaf(w1, e.x, cx); cy = fmaf(w1, e.y, cy);
                      cz = fmaf(w1, e.z, cz); cw = fmaf(w1, e.w, cw);
        e = col[512]; cx = fmaf(w2, e.x, cx); cy = fmaf(w2, e.y, cy);
                      cz = fmaf(w2, e.z, cz); cw = fmaf(w2, e.w, cw);
        e = col[768]; cx = fmaf(w3, e.x, cx); cy = fmaf(w3, e.y, cy);
                      cz = fmaf(w3, e.z, cz); cw = fmaf(w3, e.w, cw);
    };

    stage(0, 0);
    __syncthreads();
#pragma unroll
    for (int p = 0; p < 8; p++) {
        if (p < 7) stage(p + 1, (p + 1) & 1);   // loads issue before consume VALU
        consume(p & 1);
        __syncthreads();
    }

    float4 r4; r4.x = cx; r4.y = cy; r4.z = cz; r4.w = cw;
    ((float4*)g_cp)[((size_t)tc * BB + b) * (ENCD / 4) + tid] = r4;
    if (tid == 0) { g_m[tc * BB + b] = M; g_s[tc * BB + b] = S; }
}

// ---------------------------------------------------------------------------
// K2: combine 32 chunk partials per batch with global max/sum correction.
// grid (32 b, 8 dq) = 256 blocks x 128 thr = 1 block/CU; thread owns one d.
// Also initializes out-mel with proj_b (k_gates atomicAdds partials onto it;
// out is re-poisoned every replay so this init must run every launch).
// ---------------------------------------------------------------------------
__global__ __launch_bounds__(128) void k_combine(const float* __restrict__ pb,
                                                 float* __restrict__ out) {
    __shared__ float wgt[NTT];
    int b = blockIdx.x, dq = blockIdx.y, tid = threadIdx.x;
    if (dq == 0 && tid < MELD) out[b * MELD + tid] = pb[tid];
    float M = -1e30f;
#pragma unroll
    for (int tt = 0; tt < NTT; tt++) M = fmaxf(M, g_m[tt * BB + b]);
    float S = 0.f;
#pragma unroll
    for (int tt = 0; tt < NTT; tt++) S += g_s[tt * BB + b] * __expf(g_m[tt * BB + b] - M);
    if (tid < NTT) wgt[tid] = __expf(g_m[tid * BB + b] - M) * __fdividef(1.f, S);
    __syncthreads();
    int d = dq * 128 + tid;
    float acc = 0.f;
#pragma unroll 8
    for (int tt = 0; tt < NTT; tt++)
        acc = fmaf(wgt[tt], g_cp[((size_t)tt * BB + b) * ENCD + d], acc);
    g_ctx[b * ENCD + d] = acc;
}

// ---------------------------------------------------------------------------
// K3: z partials. grid 512 = 32 jt (128 j) x 16 kc (KCH=136; last = 88).
// Exactly 2 blocks/CU (no tail), 8 waves/CU for latency hiding.
// 256 thr = 128 j x 2 k-halves (rows 72/64; last chunk 48/40, all /8).
// x staged in LDS for all 32 batches; halves LDS-combined before store.
// ---------------------------------------------------------------------------
__global__ __launch_bounds__(256) void k_zmm(const float* __restrict__ pm,
                                             const float* __restrict__ h,
                                             const float* __restrict__ kern,
                                             const float* __restrict__ reck) {
    __shared__ float xs[KCH * 32];       // 17.4 KB
    __shared__ float sacc[32 * 128];     // 16 KB: khalf-1 partials [b][jl]
    int jt = blockIdx.x & 31, kc = blockIdx.x >> 5;
    int k0 = kc * KCH;
    int kcount = min(KCH, KTOT - k0);    // 136 or 88
    int tid = threadIdx.x;
    for (int idx = tid; idx < kcount * 32; idx += 256) {
        int kk = idx >> 5, b = idx & 31;
        int k = k0 + kk;
        float v;
        if (k < MELD)             v = pm[b * MELD + k];
        else if (k < MELD + ENCD) v = g_ctx[b * ENCD + (k - MELD)];
        else                      v = h[b * DECD + (k - MELD - ENCD)];
        xs[idx] = v;
    }
    __syncthreads();
    int jl = tid & 127, kh = tid >> 7;
    int j = jt * 128 + jl;
    int split = (kcount == KCH) ? 72 : 48;    // both halves divisible by 8
    int kb = kh ? split : 0;
    int ke = kh ? kcount : split;
    float acc[32];
#pragma unroll
    for (int b = 0; b < 32; b++) acc[b] = 0.f;
    for (int kk0 = kb; kk0 < ke; kk0 += 8) {
        float w[8];
#pragma unroll
        for (int i = 0; i < 8; i++) {
            int k = k0 + kk0 + i;
            w[i] = (k < MELD + ENCD) ? kern[(size_t)k * NZ + j]
                                     : reck[(size_t)(k - MELD - ENCD) * NZ + j];
        }
#pragma unroll
        for (int i = 0; i < 8; i++) {
            const float* xr = xs + (kk0 + i) * 32;
#pragma unroll
            for (int b = 0; b < 32; b++) acc[b] = fmaf(xr[b], w[i], acc[b]);
        }
    }
    if (kh) {
#pragma unroll
        for (int b = 0; b < 32; b++) sacc[b * 128 + jl] = acc[b];
    }
    __syncthreads();
    if (!kh) {
#pragma unroll
        for (int b = 0; b < 32; b++)
            g_zp[((size_t)kc * BB + b) * NZ + j] = acc[b] + sacc[b * 128 + jl];
    }
}

// ---------------------------------------------------------------------------
// K4: z-sum + gates + FUSED proj partial.
// grid 512 = 32 b x 16 jq (j-tile 64); kc-sum (16 chunks) split 4/4/4/4
// across thread groups, LDS reduce; grp0 computes h_new/c_new, writes out
// h/c and stages h_new in LDS. Epilogue: 80 threads compute this block's
// 64-j partial of mel[b,m] = sum_j h_new*pw[j,m] and atomicAdd onto the
// pb-initialized out-mel (16 partials/elem; fp32 atomic order noise ~1e-6).
// out: mel[0,2560) h[2560,35328) c[35328,68096)
// ---------------------------------------------------------------------------
__global__ __launch_bounds__(256) void k_gates(const float* __restrict__ bias,
                                               const float* __restrict__ c,
                                               const float* __restrict__ pw,
                                               float* __restrict__ out) {
    __shared__ float sacc[4][4][64];   // [grp][gate][jl]
    __shared__ float lh[64];
    int b = blockIdx.x >> 4, jq = blockIdx.x & 15;
    int jl = threadIdx.x & 63, grp = threadIdx.x >> 6;
    int j = jq * 64 + jl;
    int kc0 = grp * 4;
    int kc1 = kc0 + 4;
    float zi = 0.f, zf = 0.f, zg = 0.f, zo = 0.f;
    for (int kc = kc0; kc < kc1; kc++) {
        const float* zp = g_zp + ((size_t)kc * BB + b) * NZ;
        zi += zp[j];
        zf += zp[1024 + j];
        zg += zp[2048 + j];
        zo += zp[3072 + j];
    }
    sacc[grp][0][jl] = zi; sacc[grp][1][jl] = zf;
    sacc[grp][2][jl] = zg; sacc[grp][3][jl] = zo;
    __syncthreads();
    if (grp == 0) {
        zi = sacc[0][0][jl] + sacc[1][0][jl] + sacc[2][0][jl] + sacc[3][0][jl] + bias[j];
        zf = sacc[0][1][jl] + sacc[1][1][jl] + sacc[2][1][jl] + sacc[3][1][jl] + bias[1024 + j];
        zg = sacc[0][2][jl] + sacc[1][2][jl] + sacc[2][2][jl] + sacc[3][2][jl] + bias[2048 + j];
        zo = sacc[0][3][jl] + sacc[1][3][jl] + sacc[2][3][jl] + sacc[3][3][jl] + bias[3072 + j];
        int idx = b * 1024 + j;
        float cn = sigmoid_fast(zf) * c[idx] + sigmoid_fast(zi) * tanh_fast(zg);
        float hn = sigmoid_fast(zo) * tanh_fast(cn);
        lh[jl] = hn;
        out[2560 + idx] = hn;
        out[35328 + idx] = cn;
    }
    __syncthreads();
    if (threadIdx.x < MELD) {
        int m = threadIdx.x;
        const float* pwp = pw + (size_t)(jq * 64) * MELD + m;
        float acc = 0.f;
#pragma unroll 8
        for (int jj = 0; jj < 64; jj++) acc = fmaf(lh[jj], pwp[jj * MELD], acc);
        atomicAdd(&out[b * MELD + m], acc);
    }
}

extern "C" void kernel_launch(void* const* d_in, const int* in_sizes, int n_in,
                              void* d_out, int out_size, void* d_ws, size_t ws_size,
                              hipStream_t stream) {
    const float* pm   = (const float*)d_in[0];   // prev_mel_frame [32,80]
    const float* enc  = (const float*)d_in[1];   // encoder_outputs [32,1024,1024]
    const float* h    = (const float*)d_in[2];   // h [32,1024]
    const float* c    = (const float*)d_in[3];   // c [32,1024]
    const float* asc  = (const float*)d_in[4];   // attn_scale [1024]
    const float* kern = (const float*)d_in[5];   // kernel [1104,4096]
    const float* reck = (const float*)d_in[6];   // rec_kernel [1024,4096]
    const float* bias = (const float*)d_in[7];   // bias [4096]
    const float* pw   = (const float*)d_in[8];   // proj_w [1024,80]
    const float* pb   = (const float*)d_in[9];   // proj_b [80]
    float* out = (float*)d_out;                  // fp32: mel | h_new | c_new

    k_attn   <<<dim3(32, NTT), 256, 0, stream>>>(enc, h, asc);
    k_combine<<<dim3(32, 8), 128, 0, stream>>>(pb, out);
    k_zmm    <<<512, 256, 0, stream>>>(pm, h, kern, reck);
    k_gates  <<<512, 256, 0, stream>>>(bias, c, pw, out);
}